// Round 7
// baseline (332.055 us; speedup 1.0000x reference)
//
#include <hip/hip_runtime.h>
#include <hip/hip_bf16.h>

#define D 128
#define CHUNK 1024   // elements per scan block (256 thr x 4)
#define NXCD 8
#define HLDS 136     // LDS mean-tile row stride in bf16 (272B: 16B-aligned, 2-way bank alias = free)

typedef __attribute__((ext_vector_type(8))) short bf16x8;
typedef __attribute__((ext_vector_type(4))) float f32x4;

// ---- bf16 helpers (bit-level, RNE via __float2bfloat16) --------------------
__device__ inline float bflo(unsigned u) { return __uint_as_float(u << 16); }
__device__ inline float bfhi(unsigned u) { return __uint_as_float(u & 0xffff0000u); }
__device__ inline unsigned short f2bf(float f) {
    __hip_bfloat16 h = __float2bfloat16(f);
    return *reinterpret_cast<unsigned short*>(&h);
}
__device__ inline unsigned pack2bf(float lo, float hi) {
    return (unsigned)f2bf(lo) | ((unsigned)f2bf(hi) << 16);
}

// ---------------------------------------------------------------------------
// fp32 -> bf16 conversion
// ---------------------------------------------------------------------------
__global__ __launch_bounds__(256) void tobf16_kernel(
    const float* __restrict__ x, unsigned short* __restrict__ y, int n4)
{
    int i = blockIdx.x * blockDim.x + threadIdx.x;
    int stride = gridDim.x * blockDim.x;
    for (; i < n4; i += stride) {
        float4 v = *reinterpret_cast<const float4*>(&x[(size_t)i * 4]);
        uint2 o;
        o.x = pack2bf(v.x, v.y);
        o.y = pack2bf(v.z, v.w);
        *reinterpret_cast<uint2*>(&y[(size_t)i * 4]) = o;
    }
}

// ---------------------------------------------------------------------------
// Phase A: CSR build. off[] IMMUTABLE after scan3 (plain-store -> plain-read);
// cur[] scan3-initialized, RMW'd by scatter, dead afterwards.
// ---------------------------------------------------------------------------
__global__ __launch_bounds__(256) void hist_kernel(
    const int* __restrict__ src, const int* __restrict__ dst,
    int* __restrict__ cnt, int E, int N)
{
    int i = blockIdx.x * blockDim.x + threadIdx.x;
    int stride = gridDim.x * blockDim.x;
    for (int e = i; e < E; e += stride) {
        atomicAdd(&cnt[dst[e]], 1);
        atomicAdd(&cnt[N + src[e]], 1);
    }
}

__global__ __launch_bounds__(256) void scan1_kernel(
    const int* __restrict__ cnt, int* __restrict__ blk, int n2)
{
    __shared__ int red[256];
    const int b = blockIdx.x, t = threadIdx.x;
    const int base = b * CHUNK + t * 4;
    int s = 0;
    if (base + 3 < n2) {
        int4 v = *reinterpret_cast<const int4*>(&cnt[base]);
        s = v.x + v.y + v.z + v.w;
    } else {
        for (int j = 0; j < 4; ++j) { int idx = base + j; if (idx < n2) s += cnt[idx]; }
    }
    red[t] = s; __syncthreads();
    for (int o = 128; o > 0; o >>= 1) { if (t < o) red[t] += red[t + o]; __syncthreads(); }
    if (t == 0) blk[b] = red[0];
}

__global__ __launch_bounds__(256) void scan2_kernel(int* __restrict__ blk, int NB)
{
    __shared__ int sh[256];
    const int t = threadIdx.x;
    sh[t] = (t < NB) ? blk[t] : 0;
    __syncthreads();
    for (int o = 1; o < 256; o <<= 1) {
        int v = (t >= o) ? sh[t - o] : 0;
        __syncthreads();
        sh[t] += v;
        __syncthreads();
    }
    if (t < NB) blk[t] = (t > 0) ? sh[t - 1] : 0;   // exclusive
}

__global__ __launch_bounds__(256) void scan3_kernel(
    const int* __restrict__ cnt, const int* __restrict__ blk,
    int* __restrict__ off, int* __restrict__ cur, int n2, int total)
{
    __shared__ int sh[256];
    const int b = blockIdx.x, t = threadIdx.x;
    const int base = b * CHUNK + t * 4;
    int v[4]; int s = 0;
    for (int j = 0; j < 4; ++j) { int idx = base + j; v[j] = (idx < n2) ? cnt[idx] : 0; s += v[j]; }
    sh[t] = s; __syncthreads();
    for (int o = 1; o < 256; o <<= 1) {
        int x = (t >= o) ? sh[t - o] : 0;
        __syncthreads();
        sh[t] += x;
        __syncthreads();
    }
    int excl = blk[b] + ((t > 0) ? sh[t - 1] : 0);
    for (int j = 0; j < 4; ++j) {
        int idx = base + j;
        if (idx < n2) { off[idx] = excl; cur[idx] = excl; }
        excl += v[j];
    }
    if (b == 0 && t == 0) off[n2] = total;
}

// ---------------------------------------------------------------------------
// Scatter edge ids, node-range partitioned for XCD write locality (R6-proven).
// ---------------------------------------------------------------------------
__global__ __launch_bounds__(256) void scatter_ids_kernel(
    const int* __restrict__ src, const int* __restrict__ dst,
    int* __restrict__ cur, int* __restrict__ csr,
    int E, int N, int npr)
{
    const int grp = blockIdx.x & (NXCD - 1);
    const int bIn = blockIdx.x >> 3;
    const int nbk = gridDim.x >> 3;
    const int lo = grp * npr;
    const int hi = lo + npr;

    int i = bIn * 256 + threadIdx.x;
    const int stride = nbk * 256;
    for (int e = i; e < E; e += stride) {
        const int s = src[e];
        const int d = dst[e];
        if (d >= lo && d < hi) {
            int p = atomicAdd(&cur[d], 1);
            csr[p] = s;
        }
        if (s >= lo && s < hi) {
            int p2 = atomicAdd(&cur[N + s], 1);
            csr[p2] = d;
        }
    }
}

// ---------------------------------------------------------------------------
// FUSED mean-gather + GEMM(384->128) + ReLU.
// Block = 256 thr = 4 waves, 64 output rows.
// Phase 1: 16 groups x 16 lanes stage 128 mean segments (64 fwd + 64 bwd)
//   into LDS as bf16 (fp32 accumulate). Group g handles 8 consecutive
//   segments -> degree variance smooths (Poisson sum). Lane l owns cols
//   [8l, 8l+8). Rows >= N (tail block) write zeros (no OOB off/csr reads;
//   MFMA A-rows only affect their own out rows, which are never stored).
// Phase 2: per wave 16 rows x 128 cols, K=384 in 12 steps: A-frag from
//   global featb (k<128) or LDS mean tile (k>=128, ds_read_b128, 2-way
//   bank alias = free), B-frag from L2-resident Wb. m89-verified layouts.
// Deletes the 102MB meanb HBM round-trip and one kernel launch.
// ---------------------------------------------------------------------------
__global__ __launch_bounds__(256) void fused_mean_gemm_kernel(
    const unsigned short* __restrict__ featb,
    const unsigned short* __restrict__ Wb,      // [128][384] bf16
    const int* __restrict__ off,
    const int* __restrict__ csr,
    float* __restrict__ out, int N)
{
    __shared__ unsigned short mean_lds[128 * HLDS];   // 34 KB

    const int t = threadIdx.x;
    const int block_row = blockIdx.x * 64;

    // ---- Phase 1: gather means into LDS ----
    {
        const int g = t >> 4;       // group 0..15
        const int l = t & 15;       // lane in group; cols [8l, 8l+8)
        for (int j = 0; j < 8; ++j) {
            const int s = g * 8 + j;                 // LDS row 0..127
            const int rrow = block_row + (s & 63);
            float a0=0,a1=0,a2=0,a3=0,a4=0,a5=0,a6=0,a7=0;
            if (rrow < N) {
                const int seg = (s < 64) ? rrow : (N + rrow);
                const int beg = off[seg], end = off[seg + 1];
                int e = beg;
                for (; e + 1 < end; e += 2) {
                    const int n0 = csr[e], n1 = csr[e + 1];
                    const uint4 v0 = *reinterpret_cast<const uint4*>(featb + (size_t)n0 * D + l * 8);
                    const uint4 v1 = *reinterpret_cast<const uint4*>(featb + (size_t)n1 * D + l * 8);
                    a0 += bflo(v0.x) + bflo(v1.x); a1 += bfhi(v0.x) + bfhi(v1.x);
                    a2 += bflo(v0.y) + bflo(v1.y); a3 += bfhi(v0.y) + bfhi(v1.y);
                    a4 += bflo(v0.z) + bflo(v1.z); a5 += bfhi(v0.z) + bfhi(v1.z);
                    a6 += bflo(v0.w) + bflo(v1.w); a7 += bfhi(v0.w) + bfhi(v1.w);
                }
                if (e < end) {
                    const int n0 = csr[e];
                    const uint4 v0 = *reinterpret_cast<const uint4*>(featb + (size_t)n0 * D + l * 8);
                    a0 += bflo(v0.x); a1 += bfhi(v0.x);
                    a2 += bflo(v0.y); a3 += bfhi(v0.y);
                    a4 += bflo(v0.z); a5 += bfhi(v0.z);
                    a6 += bflo(v0.w); a7 += bfhi(v0.w);
                }
                const int deg = end - beg;
                const float inv = 1.0f / (float)((deg > 1) ? deg : 1);
                a0 *= inv; a1 *= inv; a2 *= inv; a3 *= inv;
                a4 *= inv; a5 *= inv; a6 *= inv; a7 *= inv;
            }
            uint4 o;
            o.x = pack2bf(a0, a1);
            o.y = pack2bf(a2, a3);
            o.z = pack2bf(a4, a5);
            o.w = pack2bf(a6, a7);
            *reinterpret_cast<uint4*>(&mean_lds[s * HLDS + l * 8]) = o;
        }
    }
    __syncthreads();

    // ---- Phase 2: MFMA GEMM ----
    const int wv = t >> 6;
    const int lane = t & 63;
    const int r = lane & 15;
    const int kb = (lane >> 4) * 8;

    const int row0 = blockIdx.x * 64 + wv * 16;
    const int row = row0 + r;
    const int rowc = (row < N) ? row : (N - 1);

    f32x4 acc[8];
#pragma unroll
    for (int n = 0; n < 8; ++n) acc[n] = (f32x4){0.f, 0.f, 0.f, 0.f};

    const unsigned short* h0 = featb + (size_t)rowc * D;

#pragma unroll
    for (int k0 = 0; k0 < 384; k0 += 32) {
        bf16x8 a;
        if (k0 < 128) {
            a = *reinterpret_cast<const bf16x8*>(h0 + k0 + kb);
        } else {
            const int sRow = wv * 16 + r + ((k0 < 256) ? 0 : 64);
            const int ko = (k0 & 127) + kb;
            a = *reinterpret_cast<const bf16x8*>(&mean_lds[sRow * HLDS + ko]);
        }
#pragma unroll
        for (int n = 0; n < 8; ++n) {
            const int c = n * 16 + r;
            const bf16x8 b = *reinterpret_cast<const bf16x8*>(Wb + (size_t)c * 384 + k0 + kb);
            acc[n] = __builtin_amdgcn_mfma_f32_16x16x32_bf16(a, b, acc[n], 0, 0, 0);
        }
    }

    const int ro = row0 + (lane >> 4) * 4;
#pragma unroll
    for (int n = 0; n < 8; ++n) {
        const int c = n * 16 + r;
#pragma unroll
        for (int i = 0; i < 4; ++i) {
            const int rr2 = ro + i;
            if (rr2 < N) out[(size_t)rr2 * D + c] = fmaxf(acc[n][i], 0.0f);
        }
    }
}

// ---------------------------------------------------------------------------
extern "C" void kernel_launch(void* const* d_in, const int* in_sizes, int n_in,
                              void* d_out, int out_size, void* d_ws, size_t ws_size,
                              hipStream_t stream) {
    const float* feat = (const float*)d_in[0];
    const float* W    = (const float*)d_in[1];
    const int*   ei   = (const int*)d_in[2];
    float*       out  = (float*)d_out;

    const int E = in_sizes[2] / 2;           // 800000
    const int N = in_sizes[0] / D;           // 100000
    const int n2 = 2 * N;
    const int* src = ei;
    const int* dst = ei + E;

    // ws layout (4B units then 2B units, all 16B-aligned):
    // cnt[n2] | cur[n2] | off[n2+4] | blk[256] | csr[2E] |
    // featb[N*D] u16 | Wb[128*384] u16
    int* cnt = (int*)d_ws;
    int* cur = cnt + n2;
    int* off = cur + n2;
    int* blk = off + (n2 + 4);
    int* csr = blk + 256;
    unsigned short* featb = (unsigned short*)(csr + 2 * E);
    unsigned short* Wb    = featb + (size_t)N * D;

    // zero cnt only (cur and off are fully initialized by scan3)
    hipMemsetAsync(cnt, 0, (size_t)n2 * sizeof(int), stream);

    const int NB = (n2 + CHUNK - 1) / CHUNK; // 196
    const int npr = (N + NXCD - 1) / NXCD;   // 12500 nodes per range

    tobf16_kernel<<<2048, 256, 0, stream>>>(feat, featb, N * D / 4);
    tobf16_kernel<<<48, 256, 0, stream>>>(W, Wb, 128 * 384 / 4);

    hist_kernel<<<2048, 256, 0, stream>>>(src, dst, cnt, E, N);
    scan1_kernel<<<NB, 256, 0, stream>>>(cnt, blk, n2);
    scan2_kernel<<<1, 256, 0, stream>>>(blk, NB);
    scan3_kernel<<<NB, 256, 0, stream>>>(cnt, blk, off, cur, n2, 2 * E);
    scatter_ids_kernel<<<2048, 256, 0, stream>>>(src, dst, cur, csr, E, N, npr);

    fused_mean_gemm_kernel<<<(N + 63) / 64, 256, 0, stream>>>(featb, Wb, off, csr, out, N);
}

// Round 8
// 331.840 us; speedup vs baseline: 1.0006x; 1.0006x over previous
//
#include <hip/hip_runtime.h>
#include <hip/hip_bf16.h>

#define D 128
#define CHUNK 1024   // elements per scan block (256 thr x 4)
#define NXCD 8
#define WSTRIDE 36   // LDS W row stride in bf16: 72B -> banks 18r%32 distinct for r=0..15

typedef __attribute__((ext_vector_type(8))) short bf16x8;
typedef __attribute__((ext_vector_type(4))) float f32x4;

// ---- bf16 helpers (bit-level, RNE via __float2bfloat16) --------------------
__device__ inline float bflo(unsigned u) { return __uint_as_float(u << 16); }
__device__ inline float bfhi(unsigned u) { return __uint_as_float(u & 0xffff0000u); }
__device__ inline unsigned short f2bf(float f) {
    __hip_bfloat16 h = __float2bfloat16(f);
    return *reinterpret_cast<unsigned short*>(&h);
}
__device__ inline unsigned pack2bf(float lo, float hi) {
    return (unsigned)f2bf(lo) | ((unsigned)f2bf(hi) << 16);
}

// ---------------------------------------------------------------------------
// fp32 -> bf16 conversion: feat and W in ONE launch (grid-stride over both).
// ---------------------------------------------------------------------------
__global__ __launch_bounds__(256) void tobf16_kernel(
    const float* __restrict__ feat, unsigned short* __restrict__ featb, int n4f,
    const float* __restrict__ W, unsigned short* __restrict__ Wb, int n4w)
{
    int i = blockIdx.x * blockDim.x + threadIdx.x;
    int stride = gridDim.x * blockDim.x;
    const int n4 = n4f + n4w;
    for (; i < n4; i += stride) {
        const float* x; unsigned short* y; int j;
        if (i < n4f) { x = feat; y = featb; j = i; }
        else         { x = W;    y = Wb;    j = i - n4f; }
        float4 v = *reinterpret_cast<const float4*>(&x[(size_t)j * 4]);
        uint2 o;
        o.x = pack2bf(v.x, v.y);
        o.y = pack2bf(v.z, v.w);
        *reinterpret_cast<uint2*>(&y[(size_t)j * 4]) = o;
    }
}

// ---------------------------------------------------------------------------
// Phase A: CSR build. off[] IMMUTABLE after scan3 (plain-store -> plain-read);
// cur[] scan3-initialized, RMW'd by scatter, dead afterwards.
// ---------------------------------------------------------------------------
__global__ __launch_bounds__(256) void hist_kernel(
    const int* __restrict__ src, const int* __restrict__ dst,
    int* __restrict__ cnt, int E, int N)
{
    int i = blockIdx.x * blockDim.x + threadIdx.x;
    int stride = gridDim.x * blockDim.x;
    for (int e = i; e < E; e += stride) {
        atomicAdd(&cnt[dst[e]], 1);
        atomicAdd(&cnt[N + src[e]], 1);
    }
}

__global__ __launch_bounds__(256) void scan1_kernel(
    const int* __restrict__ cnt, int* __restrict__ blk, int n2)
{
    __shared__ int red[256];
    const int b = blockIdx.x, t = threadIdx.x;
    const int base = b * CHUNK + t * 4;
    int s = 0;
    if (base + 3 < n2) {
        int4 v = *reinterpret_cast<const int4*>(&cnt[base]);
        s = v.x + v.y + v.z + v.w;
    } else {
        for (int j = 0; j < 4; ++j) { int idx = base + j; if (idx < n2) s += cnt[idx]; }
    }
    red[t] = s; __syncthreads();
    for (int o = 128; o > 0; o >>= 1) { if (t < o) red[t] += red[t + o]; __syncthreads(); }
    if (t == 0) blk[b] = red[0];
}

__global__ __launch_bounds__(256) void scan2_kernel(int* __restrict__ blk, int NB)
{
    __shared__ int sh[256];
    const int t = threadIdx.x;
    sh[t] = (t < NB) ? blk[t] : 0;
    __syncthreads();
    for (int o = 1; o < 256; o <<= 1) {
        int v = (t >= o) ? sh[t - o] : 0;
        __syncthreads();
        sh[t] += v;
        __syncthreads();
    }
    if (t < NB) blk[t] = (t > 0) ? sh[t - 1] : 0;   // exclusive
}

__global__ __launch_bounds__(256) void scan3_kernel(
    const int* __restrict__ cnt, const int* __restrict__ blk,
    int* __restrict__ off, int* __restrict__ cur, int n2, int total)
{
    __shared__ int sh[256];
    const int b = blockIdx.x, t = threadIdx.x;
    const int base = b * CHUNK + t * 4;
    int v[4]; int s = 0;
    for (int j = 0; j < 4; ++j) { int idx = base + j; v[j] = (idx < n2) ? cnt[idx] : 0; s += v[j]; }
    sh[t] = s; __syncthreads();
    for (int o = 1; o < 256; o <<= 1) {
        int x = (t >= o) ? sh[t - o] : 0;
        __syncthreads();
        sh[t] += x;
        __syncthreads();
    }
    int excl = blk[b] + ((t > 0) ? sh[t - 1] : 0);
    for (int j = 0; j < 4; ++j) {
        int idx = base + j;
        if (idx < n2) { off[idx] = excl; cur[idx] = excl; }
        excl += v[j];
    }
    if (b == 0 && t == 0) off[n2] = total;
}

// ---------------------------------------------------------------------------
// Scatter edge ids, node-range partitioned for XCD write locality (R6-proven).
// ---------------------------------------------------------------------------
__global__ __launch_bounds__(256) void scatter_ids_kernel(
    const int* __restrict__ src, const int* __restrict__ dst,
    int* __restrict__ cur, int* __restrict__ csr,
    int E, int N, int npr)
{
    const int grp = blockIdx.x & (NXCD - 1);
    const int bIn = blockIdx.x >> 3;
    const int nbk = gridDim.x >> 3;
    const int lo = grp * npr;
    const int hi = lo + npr;

    int i = bIn * 256 + threadIdx.x;
    const int stride = nbk * 256;
    for (int e = i; e < E; e += stride) {
        const int s = src[e];
        const int d = dst[e];
        if (d >= lo && d < hi) {
            int p = atomicAdd(&cur[d], 1);
            csr[p] = s;
        }
        if (s >= lo && s < hi) {
            int p2 = atomicAdd(&cur[N + s], 1);
            csr[p2] = d;
        }
    }
}

// ---------------------------------------------------------------------------
// Phase B: gather means in bf16 (R6-proven). 16 lanes per segment; lane l
// owns bf16 columns [8l, 8l+8). Bounds from IMMUTABLE off.
// ---------------------------------------------------------------------------
__global__ __launch_bounds__(256) void gather_mean_kernel(
    const unsigned short* __restrict__ featb, const int* __restrict__ off,
    const int* __restrict__ csr, unsigned short* __restrict__ meanb, int n2)
{
    const int tid = blockIdx.x * 256 + threadIdx.x;
    const int seg = tid >> 4;
    const int l = tid & 15;
    if (seg >= n2) return;

    const int beg = off[seg], end = off[seg + 1];
    float a0=0,a1=0,a2=0,a3=0,a4=0,a5=0,a6=0,a7=0;

    int e = beg;
    for (; e + 1 < end; e += 2) {
        const int n0 = csr[e], n1 = csr[e + 1];
        const uint4 v0 = *reinterpret_cast<const uint4*>(featb + (size_t)n0 * D + l * 8);
        const uint4 v1 = *reinterpret_cast<const uint4*>(featb + (size_t)n1 * D + l * 8);
        a0 += bflo(v0.x) + bflo(v1.x); a1 += bfhi(v0.x) + bfhi(v1.x);
        a2 += bflo(v0.y) + bflo(v1.y); a3 += bfhi(v0.y) + bfhi(v1.y);
        a4 += bflo(v0.z) + bflo(v1.z); a5 += bfhi(v0.z) + bfhi(v1.z);
        a6 += bflo(v0.w) + bflo(v1.w); a7 += bfhi(v0.w) + bfhi(v1.w);
    }
    if (e < end) {
        const int n0 = csr[e];
        const uint4 v0 = *reinterpret_cast<const uint4*>(featb + (size_t)n0 * D + l * 8);
        a0 += bflo(v0.x); a1 += bfhi(v0.x);
        a2 += bflo(v0.y); a3 += bfhi(v0.y);
        a4 += bflo(v0.z); a5 += bfhi(v0.z);
        a6 += bflo(v0.w); a7 += bfhi(v0.w);
    }

    const int deg = end - beg;
    const float inv = 1.0f / (float)((deg > 1) ? deg : 1);
    uint4 o;
    o.x = pack2bf(a0 * inv, a1 * inv);
    o.y = pack2bf(a2 * inv, a3 * inv);
    o.z = pack2bf(a4 * inv, a5 * inv);
    o.w = pack2bf(a6 * inv, a7 * inv);
    *reinterpret_cast<uint4*>(meanb + (size_t)seg * D + l * 8) = o;
}

// ---------------------------------------------------------------------------
// Phase C: bf16 MFMA GEMM v2. Block = 512 thr = 8 waves, 128 rows/block.
// W staged in LDS (double-buffered 32-k chunks, stride 36 bf16 -> conflict-
// free ds_read_b128); one barrier per k-chunk. Operand-swapped MFMA:
// mfma(w_frag, h_frag) puts 4 consecutive out-COLS per lane -> float4 store.
// Global loads/thread: 12 A-frags + 12 W-stage (was 108 in v1).
// ---------------------------------------------------------------------------
__global__ __launch_bounds__(512) void mfma_gemm_kernel(
    const unsigned short* __restrict__ featb,
    const unsigned short* __restrict__ meanb,
    const unsigned short* __restrict__ Wb,      // [128][384] bf16
    float* __restrict__ out, int N)
{
    __shared__ unsigned short wlds[2][128 * WSTRIDE];   // 2 x 9216 B

    const int t = threadIdx.x;
    const int wv = t >> 6;          // 0..7
    const int lane = t & 63;
    const int r = lane & 15;
    const int q = lane >> 4;        // 0..3
    const int kb = q * 8;

    const int row0 = blockIdx.x * 128 + wv * 16;
    const int row = row0 + r;
    const int rowc = (row < N) ? row : (N - 1);

    // W staging: thread t loads Wb[sc][k0 + sq*8 .. +8)
    const int sc = t >> 2;          // 0..127
    const int sq = t & 3;           // 0..3

    f32x4 acc[8];
#pragma unroll
    for (int n = 0; n < 8; ++n) acc[n] = (f32x4){0.f, 0.f, 0.f, 0.f};

    const unsigned short* h0 = featb + (size_t)rowc * D;
    const unsigned short* h1 = meanb + (size_t)rowc * D;
    const unsigned short* h2 = meanb + ((size_t)N + rowc) * D;

    // prologue: stage chunk 0
    {
        uint4 g = *reinterpret_cast<const uint4*>(Wb + (size_t)sc * 384 + sq * 8);
        *reinterpret_cast<uint4*>(
            reinterpret_cast<char*>(&wlds[0][0]) + sc * (WSTRIDE * 2) + sq * 16) = g;
    }
    __syncthreads();

#pragma unroll
    for (int ci = 0; ci < 12; ++ci) {
        const int k0 = ci * 32;
        uint4 gn;
        if (ci < 11)
            gn = *reinterpret_cast<const uint4*>(Wb + (size_t)sc * 384 + (k0 + 32) + sq * 8);

        const unsigned short* hs = (k0 < 128) ? h0 : (k0 < 256) ? h1 : h2;
        const bf16x8 bh = *reinterpret_cast<const bf16x8*>(hs + (k0 & 127) + kb);

        const char* wl = reinterpret_cast<const char*>(&wlds[ci & 1][0]);
#pragma unroll
        for (int n = 0; n < 8; ++n) {
            const int c = n * 16 + r;
            const bf16x8 aw = *reinterpret_cast<const bf16x8*>(wl + c * (WSTRIDE * 2) + kb * 2);
            acc[n] = __builtin_amdgcn_mfma_f32_16x16x32_bf16(aw, bh, acc[n], 0, 0, 0);
        }

        if (ci < 11) {
            *reinterpret_cast<uint4*>(
                reinterpret_cast<char*>(&wlds[(ci + 1) & 1][0]) + sc * (WSTRIDE * 2) + sq * 16) = gn;
        }
        __syncthreads();
    }

    // epilogue: lane (q,r) holds out[row0+r][n*16 + q*4 + i], i=0..3
    if (row < N) {
        float* orow = out + (size_t)row * D;
#pragma unroll
        for (int n = 0; n < 8; ++n) {
            float4 v;
            v.x = fmaxf(acc[n][0], 0.0f);
            v.y = fmaxf(acc[n][1], 0.0f);
            v.z = fmaxf(acc[n][2], 0.0f);
            v.w = fmaxf(acc[n][3], 0.0f);
            *reinterpret_cast<float4*>(orow + n * 16 + q * 4) = v;
        }
    }
}

// ---------------------------------------------------------------------------
extern "C" void kernel_launch(void* const* d_in, const int* in_sizes, int n_in,
                              void* d_out, int out_size, void* d_ws, size_t ws_size,
                              hipStream_t stream) {
    const float* feat = (const float*)d_in[0];
    const float* W    = (const float*)d_in[1];
    const int*   ei   = (const int*)d_in[2];
    float*       out  = (float*)d_out;

    const int E = in_sizes[2] / 2;           // 800000
    const int N = in_sizes[0] / D;           // 100000
    const int n2 = 2 * N;
    const int* src = ei;
    const int* dst = ei + E;

    // ws layout (4B units then 2B units, all 16B-aligned):
    // cnt[n2] | cur[n2] | off[n2+4] | blk[256] | csr[2E] |
    // featb[N*D] u16 | Wb[128*384] u16 | meanb[n2*D] u16
    int* cnt = (int*)d_ws;
    int* cur = cnt + n2;
    int* off = cur + n2;
    int* blk = off + (n2 + 4);
    int* csr = blk + 256;
    unsigned short* featb = (unsigned short*)(csr + 2 * E);
    unsigned short* Wb    = featb + (size_t)N * D;
    unsigned short* meanb = Wb + 128 * 384;

    // zero cnt only (cur and off are fully initialized by scan3)
    hipMemsetAsync(cnt, 0, (size_t)n2 * sizeof(int), stream);

    const int NB = (n2 + CHUNK - 1) / CHUNK; // 196
    const int npr = (N + NXCD - 1) / NXCD;   // 12500 nodes per range

    tobf16_kernel<<<2048, 256, 0, stream>>>(feat, featb, N * D / 4,
                                            W, Wb, 128 * 384 / 4);

    hist_kernel<<<2048, 256, 0, stream>>>(src, dst, cnt, E, N);
    scan1_kernel<<<NB, 256, 0, stream>>>(cnt, blk, n2);
    scan2_kernel<<<1, 256, 0, stream>>>(blk, NB);
    scan3_kernel<<<NB, 256, 0, stream>>>(cnt, blk, off, cur, n2, 2 * E);
    scatter_ids_kernel<<<2048, 256, 0, stream>>>(src, dst, cur, csr, E, N, npr);

    const int gather_blocks = (n2 * 16 + 255) / 256;   // 16 lanes per segment
    gather_mean_kernel<<<gather_blocks, 256, 0, stream>>>(featb, off, csr, meanb, n2);

    mfma_gemm_kernel<<<(N + 127) / 128, 512, 0, stream>>>(featb, meanb, Wb, out, N);
}

// Round 9
// 270.069 us; speedup vs baseline: 1.2295x; 1.2287x over previous
//
#include <hip/hip_runtime.h>
#include <hip/hip_bf16.h>

#define D 128
#define CHUNK 1024   // elements per scan block (256 thr x 4)
#define NXCD 8

typedef __attribute__((ext_vector_type(8))) short bf16x8;
typedef __attribute__((ext_vector_type(4))) float f32x4;

// ---- bf16 helpers (bit-level, RNE via __float2bfloat16) --------------------
__device__ inline float bflo(unsigned u) { return __uint_as_float(u << 16); }
__device__ inline float bfhi(unsigned u) { return __uint_as_float(u & 0xffff0000u); }
__device__ inline unsigned short f2bf(float f) {
    __hip_bfloat16 h = __float2bfloat16(f);
    return *reinterpret_cast<unsigned short*>(&h);
}
__device__ inline unsigned pack2bf(float lo, float hi) {
    return (unsigned)f2bf(lo) | ((unsigned)f2bf(hi) << 16);
}

// ---------------------------------------------------------------------------
// fp32 -> bf16 conversion: feat and W in ONE launch (grid-stride over both).
// ---------------------------------------------------------------------------
__global__ __launch_bounds__(256) void tobf16_kernel(
    const float* __restrict__ feat, unsigned short* __restrict__ featb, int n4f,
    const float* __restrict__ W, unsigned short* __restrict__ Wb, int n4w)
{
    int i = blockIdx.x * blockDim.x + threadIdx.x;
    int stride = gridDim.x * blockDim.x;
    const int n4 = n4f + n4w;
    for (; i < n4; i += stride) {
        const float* x; unsigned short* y; int j;
        if (i < n4f) { x = feat; y = featb; j = i; }
        else         { x = W;    y = Wb;    j = i - n4f; }
        float4 v = *reinterpret_cast<const float4*>(&x[(size_t)j * 4]);
        uint2 o;
        o.x = pack2bf(v.x, v.y);
        o.y = pack2bf(v.z, v.w);
        *reinterpret_cast<uint2*>(&y[(size_t)j * 4]) = o;
    }
}

// ---------------------------------------------------------------------------
// Phase A: CSR build. off[] IMMUTABLE after scan3 (plain-store -> plain-read);
// cur[] scan3-initialized, RMW'd by scatter, dead afterwards.
// ---------------------------------------------------------------------------
__global__ __launch_bounds__(256) void hist_kernel(
    const int* __restrict__ src, const int* __restrict__ dst,
    int* __restrict__ cnt, int E, int N)
{
    int i = blockIdx.x * blockDim.x + threadIdx.x;
    int stride = gridDim.x * blockDim.x;
    for (int e = i; e < E; e += stride) {
        atomicAdd(&cnt[dst[e]], 1);
        atomicAdd(&cnt[N + src[e]], 1);
    }
}

__global__ __launch_bounds__(256) void scan1_kernel(
    const int* __restrict__ cnt, int* __restrict__ blk, int n2)
{
    __shared__ int red[256];
    const int b = blockIdx.x, t = threadIdx.x;
    const int base = b * CHUNK + t * 4;
    int s = 0;
    if (base + 3 < n2) {
        int4 v = *reinterpret_cast<const int4*>(&cnt[base]);
        s = v.x + v.y + v.z + v.w;
    } else {
        for (int j = 0; j < 4; ++j) { int idx = base + j; if (idx < n2) s += cnt[idx]; }
    }
    red[t] = s; __syncthreads();
    for (int o = 128; o > 0; o >>= 1) { if (t < o) red[t] += red[t + o]; __syncthreads(); }
    if (t == 0) blk[b] = red[0];
}

__global__ __launch_bounds__(256) void scan2_kernel(int* __restrict__ blk, int NB)
{
    __shared__ int sh[256];
    const int t = threadIdx.x;
    sh[t] = (t < NB) ? blk[t] : 0;
    __syncthreads();
    for (int o = 1; o < 256; o <<= 1) {
        int v = (t >= o) ? sh[t - o] : 0;
        __syncthreads();
        sh[t] += v;
        __syncthreads();
    }
    if (t < NB) blk[t] = (t > 0) ? sh[t - 1] : 0;   // exclusive
}

__global__ __launch_bounds__(256) void scan3_kernel(
    const int* __restrict__ cnt, const int* __restrict__ blk,
    int* __restrict__ off, int* __restrict__ cur, int n2, int total)
{
    __shared__ int sh[256];
    const int b = blockIdx.x, t = threadIdx.x;
    const int base = b * CHUNK + t * 4;
    int v[4]; int s = 0;
    for (int j = 0; j < 4; ++j) { int idx = base + j; v[j] = (idx < n2) ? cnt[idx] : 0; s += v[j]; }
    sh[t] = s; __syncthreads();
    for (int o = 1; o < 256; o <<= 1) {
        int x = (t >= o) ? sh[t - o] : 0;
        __syncthreads();
        sh[t] += x;
        __syncthreads();
    }
    int excl = blk[b] + ((t > 0) ? sh[t - 1] : 0);
    for (int j = 0; j < 4; ++j) {
        int idx = base + j;
        if (idx < n2) { off[idx] = excl; cur[idx] = excl; }
        excl += v[j];
    }
    if (b == 0 && t == 0) off[n2] = total;
}

// ---------------------------------------------------------------------------
// Scatter edge ids, node-range partitioned for XCD write locality (R6-proven).
// ---------------------------------------------------------------------------
__global__ __launch_bounds__(256) void scatter_ids_kernel(
    const int* __restrict__ src, const int* __restrict__ dst,
    int* __restrict__ cur, int* __restrict__ csr,
    int E, int N, int npr)
{
    const int grp = blockIdx.x & (NXCD - 1);
    const int bIn = blockIdx.x >> 3;
    const int nbk = gridDim.x >> 3;
    const int lo = grp * npr;
    const int hi = lo + npr;

    int i = bIn * 256 + threadIdx.x;
    const int stride = nbk * 256;
    for (int e = i; e < E; e += stride) {
        const int s = src[e];
        const int d = dst[e];
        if (d >= lo && d < hi) {
            int p = atomicAdd(&cur[d], 1);
            csr[p] = s;
        }
        if (s >= lo && s < hi) {
            int p2 = atomicAdd(&cur[N + s], 1);
            csr[p2] = d;
        }
    }
}

// ---------------------------------------------------------------------------
// Phase B: gather means in bf16 (R6-proven). 16 lanes per segment; lane l
// owns bf16 columns [8l, 8l+8). Bounds from IMMUTABLE off.
// ---------------------------------------------------------------------------
__global__ __launch_bounds__(256) void gather_mean_kernel(
    const unsigned short* __restrict__ featb, const int* __restrict__ off,
    const int* __restrict__ csr, unsigned short* __restrict__ meanb, int n2)
{
    const int tid = blockIdx.x * 256 + threadIdx.x;
    const int seg = tid >> 4;
    const int l = tid & 15;
    if (seg >= n2) return;

    const int beg = off[seg], end = off[seg + 1];
    float a0=0,a1=0,a2=0,a3=0,a4=0,a5=0,a6=0,a7=0;

    int e = beg;
    for (; e + 1 < end; e += 2) {
        const int n0 = csr[e], n1 = csr[e + 1];
        const uint4 v0 = *reinterpret_cast<const uint4*>(featb + (size_t)n0 * D + l * 8);
        const uint4 v1 = *reinterpret_cast<const uint4*>(featb + (size_t)n1 * D + l * 8);
        a0 += bflo(v0.x) + bflo(v1.x); a1 += bfhi(v0.x) + bfhi(v1.x);
        a2 += bflo(v0.y) + bflo(v1.y); a3 += bfhi(v0.y) + bfhi(v1.y);
        a4 += bflo(v0.z) + bflo(v1.z); a5 += bfhi(v0.z) + bfhi(v1.z);
        a6 += bflo(v0.w) + bflo(v1.w); a7 += bfhi(v0.w) + bfhi(v1.w);
    }
    if (e < end) {
        const int n0 = csr[e];
        const uint4 v0 = *reinterpret_cast<const uint4*>(featb + (size_t)n0 * D + l * 8);
        a0 += bflo(v0.x); a1 += bfhi(v0.x);
        a2 += bflo(v0.y); a3 += bfhi(v0.y);
        a4 += bflo(v0.z); a5 += bfhi(v0.z);
        a6 += bflo(v0.w); a7 += bfhi(v0.w);
    }

    const int deg = end - beg;
    const float inv = 1.0f / (float)((deg > 1) ? deg : 1);
    uint4 o;
    o.x = pack2bf(a0 * inv, a1 * inv);
    o.y = pack2bf(a2 * inv, a3 * inv);
    o.z = pack2bf(a4 * inv, a5 * inv);
    o.w = pack2bf(a6 * inv, a7 * inv);
    *reinterpret_cast<uint4*>(meanb + (size_t)seg * D + l * 8) = o;
}

// ---------------------------------------------------------------------------
// Phase C: bf16 MFMA GEMM v3. Block = 512 thr = 8 waves, 128 rows/block.
// - All 12 h A-fragments prefetched to registers at kernel start (static
//   indices, no in-loop global A-traffic).
// - W staged in K=128 slabs (32KB), double-buffered: only 3 barriers total.
//   Next slab loaded to regs at iteration top (latency hidden under 32 MFMA
//   + 32 ds_read), written to the idle LDS buffer after compute.
// - XOR swizzle (byte ^= (col&7)<<4 within each col's 256B) -> ds_read_b128
//   2-way bank alias (free, m136); writes balanced 8 lanes/slot.
// - Operand-swapped mfma(w,h) + float4 epilogue (R8-validated layouts).
// ---------------------------------------------------------------------------
__global__ __launch_bounds__(512) void mfma_gemm_kernel(
    const unsigned short* __restrict__ featb,
    const unsigned short* __restrict__ meanb,
    const unsigned short* __restrict__ Wb,      // [128][384] bf16
    float* __restrict__ out, int N)
{
    __shared__ unsigned short wlds[2][128 * 128];   // 2 x 32KB, swizzled [col][k]

    const int t = threadIdx.x;
    const int wv = t >> 6;          // 0..7
    const int lane = t & 63;
    const int r = lane & 15;
    const int q = lane >> 4;        // 0..3

    const int row0 = blockIdx.x * 128 + wv * 16;
    const int row = row0 + r;
    const int rowc = (row < N) ? row : (N - 1);

    // ---- prefetch all 12 A-fragments ----
    const unsigned short* h0 = featb + (size_t)rowc * D;
    const unsigned short* h1 = meanb + (size_t)rowc * D;
    const unsigned short* h2 = meanb + ((size_t)N + rowc) * D;
    bf16x8 af[12];
#pragma unroll
    for (int kk = 0; kk < 4; ++kk) {
        af[kk]     = *reinterpret_cast<const bf16x8*>(h0 + kk * 32 + q * 8);
        af[4 + kk] = *reinterpret_cast<const bf16x8*>(h1 + kk * 32 + q * 8);
        af[8 + kk] = *reinterpret_cast<const bf16x8*>(h2 + kk * 32 + q * 8);
    }

    // ---- W staging: thread t owns col sc, 4 x 16B sub-chunks ----
    const int sc = t >> 2;          // 0..127
    const int sq = t & 3;           // 0..3
    const char* wsrc = reinterpret_cast<const char*>(Wb) + (size_t)sc * 768;
    const int swz = (sc & 7) << 4;

    f32x4 acc[8];
#pragma unroll
    for (int n = 0; n < 8; ++n) acc[n] = (f32x4){0.f, 0.f, 0.f, 0.f};

    // prologue: stage slab 0 into buf 0
    {
        uint4 st[4];
#pragma unroll
        for (int j = 0; j < 4; ++j)
            st[j] = *reinterpret_cast<const uint4*>(wsrc + j * 64 + sq * 16);
        char* wb0 = reinterpret_cast<char*>(&wlds[0][0]) + sc * 256;
#pragma unroll
        for (int j = 0; j < 4; ++j)
            *reinterpret_cast<uint4*>(wb0 + ((j * 64 + sq * 16) ^ swz)) = st[j];
    }
    __syncthreads();

#pragma unroll
    for (int ci = 0; ci < 3; ++ci) {
        // issue next-slab loads early (latency hides under compute below)
        uint4 nx[4];
        if (ci < 2) {
#pragma unroll
            for (int j = 0; j < 4; ++j)
                nx[j] = *reinterpret_cast<const uint4*>(
                    wsrc + (ci + 1) * 256 + j * 64 + sq * 16);
        }

        const char* wl = reinterpret_cast<const char*>(&wlds[ci & 1][0]);
#pragma unroll
        for (int kk = 0; kk < 4; ++kk) {
            const bf16x8 bh = af[ci * 4 + kk];
#pragma unroll
            for (int n = 0; n < 8; ++n) {
                const int c = n * 16 + r;
                const bf16x8 aw = *reinterpret_cast<const bf16x8*>(
                    wl + c * 256 + ((kk * 64 + q * 16) ^ ((c & 7) << 4)));
                acc[n] = __builtin_amdgcn_mfma_f32_16x16x32_bf16(aw, bh, acc[n], 0, 0, 0);
            }
        }

        if (ci < 2) {
            // write next slab to the idle buffer (write-after-read safe:
            // that buffer's reads completed before the previous barrier)
            char* wbn = reinterpret_cast<char*>(&wlds[(ci + 1) & 1][0]) + sc * 256;
#pragma unroll
            for (int j = 0; j < 4; ++j)
                *reinterpret_cast<uint4*>(wbn + ((j * 64 + sq * 16) ^ swz)) = nx[j];
            __syncthreads();
        }
    }

    // epilogue: lane (q,r) holds out[row0+r][n*16 + q*4 + i], i=0..3
    if (row < N) {
        float* orow = out + (size_t)row * D;
#pragma unroll
        for (int n = 0; n < 8; ++n) {
            float4 v;
            v.x = fmaxf(acc[n][0], 0.0f);
            v.y = fmaxf(acc[n][1], 0.0f);
            v.z = fmaxf(acc[n][2], 0.0f);
            v.w = fmaxf(acc[n][3], 0.0f);
            *reinterpret_cast<float4*>(orow + n * 16 + q * 4) = v;
        }
    }
}

// ---------------------------------------------------------------------------
extern "C" void kernel_launch(void* const* d_in, const int* in_sizes, int n_in,
                              void* d_out, int out_size, void* d_ws, size_t ws_size,
                              hipStream_t stream) {
    const float* feat = (const float*)d_in[0];
    const float* W    = (const float*)d_in[1];
    const int*   ei   = (const int*)d_in[2];
    float*       out  = (float*)d_out;

    const int E = in_sizes[2] / 2;           // 800000
    const int N = in_sizes[0] / D;           // 100000
    const int n2 = 2 * N;
    const int* src = ei;
    const int* dst = ei + E;

    // ws layout (4B units then 2B units, all 16B-aligned):
    // cnt[n2] | cur[n2] | off[n2+4] | blk[256] | csr[2E] |
    // featb[N*D] u16 | Wb[128*384] u16 | meanb[n2*D] u16
    int* cnt = (int*)d_ws;
    int* cur = cnt + n2;
    int* off = cur + n2;
    int* blk = off + (n2 + 4);
    int* csr = blk + 256;
    unsigned short* featb = (unsigned short*)(csr + 2 * E);
    unsigned short* Wb    = featb + (size_t)N * D;
    unsigned short* meanb = Wb + 128 * 384;

    // zero cnt only (cur and off are fully initialized by scan3)
    hipMemsetAsync(cnt, 0, (size_t)n2 * sizeof(int), stream);

    const int NB = (n2 + CHUNK - 1) / CHUNK; // 196
    const int npr = (N + NXCD - 1) / NXCD;   // 12500 nodes per range

    tobf16_kernel<<<2048, 256, 0, stream>>>(feat, featb, N * D / 4,
                                            W, Wb, 128 * 384 / 4);

    hist_kernel<<<2048, 256, 0, stream>>>(src, dst, cnt, E, N);
    scan1_kernel<<<NB, 256, 0, stream>>>(cnt, blk, n2);
    scan2_kernel<<<1, 256, 0, stream>>>(blk, NB);
    scan3_kernel<<<NB, 256, 0, stream>>>(cnt, blk, off, cur, n2, 2 * E);
    scatter_ids_kernel<<<2048, 256, 0, stream>>>(src, dst, cur, csr, E, N, npr);

    const int gather_blocks = (n2 * 16 + 255) / 256;   // 16 lanes per segment
    gather_mean_kernel<<<gather_blocks, 256, 0, stream>>>(featb, off, csr, meanb, n2);

    mfma_gemm_kernel<<<(N + 127) / 128, 512, 0, stream>>>(featb, meanb, Wb, out, N);
}

// Round 10
// 267.305 us; speedup vs baseline: 1.2422x; 1.0103x over previous
//
#include <hip/hip_runtime.h>
#include <hip/hip_bf16.h>

#define D 128
#define CHUNK 1024   // elements per scan block (256 thr x 4)
#define NXCD 8

typedef __attribute__((ext_vector_type(8))) short bf16x8;
typedef __attribute__((ext_vector_type(4))) float f32x4;

// ---- bf16 helpers (bit-level, RNE via __float2bfloat16) --------------------
__device__ inline float bflo(unsigned u) { return __uint_as_float(u << 16); }
__device__ inline float bfhi(unsigned u) { return __uint_as_float(u & 0xffff0000u); }
__device__ inline unsigned short f2bf(float f) {
    __hip_bfloat16 h = __float2bfloat16(f);
    return *reinterpret_cast<unsigned short*>(&h);
}
__device__ inline unsigned pack2bf(float lo, float hi) {
    return (unsigned)f2bf(lo) | ((unsigned)f2bf(hi) << 16);
}

// ---------------------------------------------------------------------------
// prep: fp32->bf16 for feat and W, PLUS degree histogram — all independent
// element-parallel work fused into one launch. Work layout:
//   [0, n4f)            : feat float4 -> bf16x4
//   [n4f, n4f+n4w)      : W float4 -> bf16x4
//   [n4f+n4w, +E)       : edge e -> two atomicAdds on cnt
// ---------------------------------------------------------------------------
__global__ __launch_bounds__(256) void prep_kernel(
    const float* __restrict__ feat, unsigned short* __restrict__ featb, int n4f,
    const float* __restrict__ W, unsigned short* __restrict__ Wb, int n4w,
    const int* __restrict__ src, const int* __restrict__ dst,
    int* __restrict__ cnt, int E, int N)
{
    int i = blockIdx.x * blockDim.x + threadIdx.x;
    const int stride = gridDim.x * blockDim.x;
    const int total = n4f + n4w + E;
    for (; i < total; i += stride) {
        if (i < n4f + n4w) {
            const float* x; unsigned short* y; int j;
            if (i < n4f) { x = feat; y = featb; j = i; }
            else         { x = W;    y = Wb;    j = i - n4f; }
            float4 v = *reinterpret_cast<const float4*>(&x[(size_t)j * 4]);
            uint2 o;
            o.x = pack2bf(v.x, v.y);
            o.y = pack2bf(v.z, v.w);
            *reinterpret_cast<uint2*>(&y[(size_t)j * 4]) = o;
        } else {
            const int e = i - n4f - n4w;
            atomicAdd(&cnt[dst[e]], 1);
            atomicAdd(&cnt[N + src[e]], 1);
        }
    }
}

// ---------------------------------------------------------------------------
// Scans (R5-proven). off[] IMMUTABLE after scan3; cur[] = off[] initialized
// by scan3, RMW'd by scatter, dead afterwards.
// ---------------------------------------------------------------------------
__global__ __launch_bounds__(256) void scan1_kernel(
    const int* __restrict__ cnt, int* __restrict__ blk, int n2)
{
    __shared__ int red[256];
    const int b = blockIdx.x, t = threadIdx.x;
    const int base = b * CHUNK + t * 4;
    int s = 0;
    if (base + 3 < n2) {
        int4 v = *reinterpret_cast<const int4*>(&cnt[base]);
        s = v.x + v.y + v.z + v.w;
    } else {
        for (int j = 0; j < 4; ++j) { int idx = base + j; if (idx < n2) s += cnt[idx]; }
    }
    red[t] = s; __syncthreads();
    for (int o = 128; o > 0; o >>= 1) { if (t < o) red[t] += red[t + o]; __syncthreads(); }
    if (t == 0) blk[b] = red[0];
}

__global__ __launch_bounds__(256) void scan2_kernel(int* __restrict__ blk, int NB)
{
    __shared__ int sh[256];
    const int t = threadIdx.x;
    sh[t] = (t < NB) ? blk[t] : 0;
    __syncthreads();
    for (int o = 1; o < 256; o <<= 1) {
        int v = (t >= o) ? sh[t - o] : 0;
        __syncthreads();
        sh[t] += v;
        __syncthreads();
    }
    if (t < NB) blk[t] = (t > 0) ? sh[t - 1] : 0;   // exclusive
}

__global__ __launch_bounds__(256) void scan3_kernel(
    const int* __restrict__ cnt, const int* __restrict__ blk,
    int* __restrict__ off, int* __restrict__ cur, int n2, int total)
{
    __shared__ int sh[256];
    const int b = blockIdx.x, t = threadIdx.x;
    const int base = b * CHUNK + t * 4;
    int v[4]; int s = 0;
    for (int j = 0; j < 4; ++j) { int idx = base + j; v[j] = (idx < n2) ? cnt[idx] : 0; s += v[j]; }
    sh[t] = s; __syncthreads();
    for (int o = 1; o < 256; o <<= 1) {
        int x = (t >= o) ? sh[t - o] : 0;
        __syncthreads();
        sh[t] += x;
        __syncthreads();
    }
    int excl = blk[b] + ((t > 0) ? sh[t - 1] : 0);
    for (int j = 0; j < 4; ++j) {
        int idx = base + j;
        if (idx < n2) { off[idx] = excl; cur[idx] = excl; }
        excl += v[j];
    }
    if (b == 0 && t == 0) off[n2] = total;
}

// ---------------------------------------------------------------------------
// Scatter edge ids, node-range partitioned for XCD write locality (R6-proven).
// ---------------------------------------------------------------------------
__global__ __launch_bounds__(256) void scatter_ids_kernel(
    const int* __restrict__ src, const int* __restrict__ dst,
    int* __restrict__ cur, int* __restrict__ csr,
    int E, int N, int npr)
{
    const int grp = blockIdx.x & (NXCD - 1);
    const int bIn = blockIdx.x >> 3;
    const int nbk = gridDim.x >> 3;
    const int lo = grp * npr;
    const int hi = lo + npr;

    int i = bIn * 256 + threadIdx.x;
    const int stride = nbk * 256;
    for (int e = i; e < E; e += stride) {
        const int s = src[e];
        const int d = dst[e];
        if (d >= lo && d < hi) {
            int p = atomicAdd(&cur[d], 1);
            csr[p] = s;
        }
        if (s >= lo && s < hi) {
            int p2 = atomicAdd(&cur[N + s], 1);
            csr[p2] = d;
        }
    }
}

// ---------------------------------------------------------------------------
// Phase B: gather means, unroll-4 for 4 independent row-loads in flight
// (latency-bound fix: R9 arithmetic showed MLP-limited at 2 in flight).
// 16 lanes per segment; lane l owns bf16 columns [8l, 8l+8).
// ---------------------------------------------------------------------------
__global__ __launch_bounds__(256) void gather_mean_kernel(
    const unsigned short* __restrict__ featb, const int* __restrict__ off,
    const int* __restrict__ csr, unsigned short* __restrict__ meanb, int n2)
{
    const int tid = blockIdx.x * 256 + threadIdx.x;
    const int seg = tid >> 4;
    const int l = tid & 15;
    if (seg >= n2) return;

    const int beg = off[seg], end = off[seg + 1];
    float a0=0,a1=0,a2=0,a3=0,a4=0,a5=0,a6=0,a7=0;

    int e = beg;
    for (; e + 3 < end; e += 4) {
        const int n0 = csr[e], n1 = csr[e + 1], n2i = csr[e + 2], n3 = csr[e + 3];
        const uint4 v0 = *reinterpret_cast<const uint4*>(featb + (size_t)n0 * D + l * 8);
        const uint4 v1 = *reinterpret_cast<const uint4*>(featb + (size_t)n1 * D + l * 8);
        const uint4 v2 = *reinterpret_cast<const uint4*>(featb + (size_t)n2i * D + l * 8);
        const uint4 v3 = *reinterpret_cast<const uint4*>(featb + (size_t)n3 * D + l * 8);
        a0 += (bflo(v0.x) + bflo(v1.x)) + (bflo(v2.x) + bflo(v3.x));
        a1 += (bfhi(v0.x) + bfhi(v1.x)) + (bfhi(v2.x) + bfhi(v3.x));
        a2 += (bflo(v0.y) + bflo(v1.y)) + (bflo(v2.y) + bflo(v3.y));
        a3 += (bfhi(v0.y) + bfhi(v1.y)) + (bfhi(v2.y) + bfhi(v3.y));
        a4 += (bflo(v0.z) + bflo(v1.z)) + (bflo(v2.z) + bflo(v3.z));
        a5 += (bfhi(v0.z) + bfhi(v1.z)) + (bfhi(v2.z) + bfhi(v3.z));
        a6 += (bflo(v0.w) + bflo(v1.w)) + (bflo(v2.w) + bflo(v3.w));
        a7 += (bfhi(v0.w) + bfhi(v1.w)) + (bfhi(v2.w) + bfhi(v3.w));
    }
    for (; e < end; ++e) {
        const int n0 = csr[e];
        const uint4 v0 = *reinterpret_cast<const uint4*>(featb + (size_t)n0 * D + l * 8);
        a0 += bflo(v0.x); a1 += bfhi(v0.x);
        a2 += bflo(v0.y); a3 += bfhi(v0.y);
        a4 += bflo(v0.z); a5 += bfhi(v0.z);
        a6 += bflo(v0.w); a7 += bfhi(v0.w);
    }

    const int deg = end - beg;
    const float inv = 1.0f / (float)((deg > 1) ? deg : 1);
    uint4 o;
    o.x = pack2bf(a0 * inv, a1 * inv);
    o.y = pack2bf(a2 * inv, a3 * inv);
    o.z = pack2bf(a4 * inv, a5 * inv);
    o.w = pack2bf(a6 * inv, a7 * inv);
    *reinterpret_cast<uint4*>(meanb + (size_t)seg * D + l * 8) = o;
}

// ---------------------------------------------------------------------------
// Phase C: bf16 MFMA GEMM v3 (R9-proven). 512 thr, 128 rows/block, K=128
// LDS slabs double-buffered (3 barriers), XOR-swizzled, all 12 A-frags
// register-prefetched, operand-swapped mfma(w,h), float4 epilogue.
// ---------------------------------------------------------------------------
__global__ __launch_bounds__(512) void mfma_gemm_kernel(
    const unsigned short* __restrict__ featb,
    const unsigned short* __restrict__ meanb,
    const unsigned short* __restrict__ Wb,      // [128][384] bf16
    float* __restrict__ out, int N)
{
    __shared__ unsigned short wlds[2][128 * 128];   // 2 x 32KB, swizzled [col][k]

    const int t = threadIdx.x;
    const int wv = t >> 6;          // 0..7
    const int lane = t & 63;
    const int r = lane & 15;
    const int q = lane >> 4;        // 0..3

    const int row0 = blockIdx.x * 128 + wv * 16;
    const int row = row0 + r;
    const int rowc = (row < N) ? row : (N - 1);

    // ---- prefetch all 12 A-fragments ----
    const unsigned short* h0 = featb + (size_t)rowc * D;
    const unsigned short* h1 = meanb + (size_t)rowc * D;
    const unsigned short* h2 = meanb + ((size_t)N + rowc) * D;
    bf16x8 af[12];
#pragma unroll
    for (int kk = 0; kk < 4; ++kk) {
        af[kk]     = *reinterpret_cast<const bf16x8*>(h0 + kk * 32 + q * 8);
        af[4 + kk] = *reinterpret_cast<const bf16x8*>(h1 + kk * 32 + q * 8);
        af[8 + kk] = *reinterpret_cast<const bf16x8*>(h2 + kk * 32 + q * 8);
    }

    // ---- W staging: thread t owns col sc, 4 x 16B sub-chunks ----
    const int sc = t >> 2;          // 0..127
    const int sq = t & 3;           // 0..3
    const char* wsrc = reinterpret_cast<const char*>(Wb) + (size_t)sc * 768;
    const int swz = (sc & 7) << 4;

    f32x4 acc[8];
#pragma unroll
    for (int n = 0; n < 8; ++n) acc[n] = (f32x4){0.f, 0.f, 0.f, 0.f};

    // prologue: stage slab 0 into buf 0
    {
        uint4 st[4];
#pragma unroll
        for (int j = 0; j < 4; ++j)
            st[j] = *reinterpret_cast<const uint4*>(wsrc + j * 64 + sq * 16);
        char* wb0 = reinterpret_cast<char*>(&wlds[0][0]) + sc * 256;
#pragma unroll
        for (int j = 0; j < 4; ++j)
            *reinterpret_cast<uint4*>(wb0 + ((j * 64 + sq * 16) ^ swz)) = st[j];
    }
    __syncthreads();

#pragma unroll
    for (int ci = 0; ci < 3; ++ci) {
        // issue next-slab loads early (latency hides under compute below)
        uint4 nx[4];
        if (ci < 2) {
#pragma unroll
            for (int j = 0; j < 4; ++j)
                nx[j] = *reinterpret_cast<const uint4*>(
                    wsrc + (ci + 1) * 256 + j * 64 + sq * 16);
        }

        const char* wl = reinterpret_cast<const char*>(&wlds[ci & 1][0]);
#pragma unroll
        for (int kk = 0; kk < 4; ++kk) {
            const bf16x8 bh = af[ci * 4 + kk];
#pragma unroll
            for (int n = 0; n < 8; ++n) {
                const int c = n * 16 + r;
                const bf16x8 aw = *reinterpret_cast<const bf16x8*>(
                    wl + c * 256 + ((kk * 64 + q * 16) ^ ((c & 7) << 4)));
                acc[n] = __builtin_amdgcn_mfma_f32_16x16x32_bf16(aw, bh, acc[n], 0, 0, 0);
            }
        }

        if (ci < 2) {
            char* wbn = reinterpret_cast<char*>(&wlds[(ci + 1) & 1][0]) + sc * 256;
#pragma unroll
            for (int j = 0; j < 4; ++j)
                *reinterpret_cast<uint4*>(wbn + ((j * 64 + sq * 16) ^ swz)) = nx[j];
            __syncthreads();
        }
    }

    // epilogue: lane (q,r) holds out[row0+r][n*16 + q*4 + i], i=0..3
    if (row < N) {
        float* orow = out + (size_t)row * D;
#pragma unroll
        for (int n = 0; n < 8; ++n) {
            float4 v;
            v.x = fmaxf(acc[n][0], 0.0f);
            v.y = fmaxf(acc[n][1], 0.0f);
            v.z = fmaxf(acc[n][2], 0.0f);
            v.w = fmaxf(acc[n][3], 0.0f);
            *reinterpret_cast<float4*>(orow + n * 16 + q * 4) = v;
        }
    }
}

// ---------------------------------------------------------------------------
extern "C" void kernel_launch(void* const* d_in, const int* in_sizes, int n_in,
                              void* d_out, int out_size, void* d_ws, size_t ws_size,
                              hipStream_t stream) {
    const float* feat = (const float*)d_in[0];
    const float* W    = (const float*)d_in[1];
    const int*   ei   = (const int*)d_in[2];
    float*       out  = (float*)d_out;

    const int E = in_sizes[2] / 2;           // 800000
    const int N = in_sizes[0] / D;           // 100000
    const int n2 = 2 * N;
    const int* src = ei;
    const int* dst = ei + E;

    // ws layout (4B units then 2B units, all 16B-aligned):
    // cnt[n2] | cur[n2] | off[n2+4] | blk[256] | csr[2E] |
    // featb[N*D] u16 | Wb[128*384] u16 | meanb[n2*D] u16
    int* cnt = (int*)d_ws;
    int* cur = cnt + n2;
    int* off = cur + n2;
    int* blk = off + (n2 + 4);
    int* csr = blk + 256;
    unsigned short* featb = (unsigned short*)(csr + 2 * E);
    unsigned short* Wb    = featb + (size_t)N * D;
    unsigned short* meanb = Wb + 128 * 384;

    // zero cnt only (cur and off are fully initialized by scan3)
    hipMemsetAsync(cnt, 0, (size_t)n2 * sizeof(int), stream);

    const int NB = (n2 + CHUNK - 1) / CHUNK; // 196
    const int npr = (N + NXCD - 1) / NXCD;   // 12500 nodes per range
    const int n4f = N * D / 4;
    const int n4w = 128 * 384 / 4;

    prep_kernel<<<2048, 256, 0, stream>>>(feat, featb, n4f, W, Wb, n4w,
                                          src, dst, cnt, E, N);

    scan1_kernel<<<NB, 256, 0, stream>>>(cnt, blk, n2);
    scan2_kernel<<<1, 256, 0, stream>>>(blk, NB);
    scan3_kernel<<<NB, 256, 0, stream>>>(cnt, blk, off, cur, n2, 2 * E);
    scatter_ids_kernel<<<2048, 256, 0, stream>>>(src, dst, cur, csr, E, N, npr);

    const int gather_blocks = (n2 * 16 + 255) / 256;   // 16 lanes per segment
    gather_mean_kernel<<<gather_blocks, 256, 0, stream>>>(featb, off, csr, meanb, n2);

    mfma_gemm_kernel<<<(N + 127) / 128, 512, 0, stream>>>(featb, meanb, Wb, out, N);
}

// Round 11
// 238.480 us; speedup vs baseline: 1.3924x; 1.1209x over previous
//
#include <hip/hip_runtime.h>
#include <hip/hip_bf16.h>

#define D 128
#define CHUNK 1024   // elements per scan block (256 thr x 4)
#define NXCD 8

typedef __attribute__((ext_vector_type(8))) short bf16x8;
typedef __attribute__((ext_vector_type(4))) float f32x4;

// ---- bf16 helpers (bit-level, RNE via __float2bfloat16) --------------------
__device__ inline float bflo(unsigned u) { return __uint_as_float(u << 16); }
__device__ inline float bfhi(unsigned u) { return __uint_as_float(u & 0xffff0000u); }
__device__ inline unsigned short f2bf(float f) {
    __hip_bfloat16 h = __float2bfloat16(f);
    return *reinterpret_cast<unsigned short*>(&h);
}
__device__ inline unsigned pack2bf(float lo, float hi) {
    return (unsigned)f2bf(lo) | ((unsigned)f2bf(hi) << 16);
}

// ---------------------------------------------------------------------------
// prep: fp32->bf16 for feat and W, PLUS degree histogram where the atomic
// RETURN value is stored as the edge's rank within its segment (rankF/rankB).
// This makes the later scatter atomic-free. Work layout:
//   [0, n4f)            : feat float4 -> bf16x4
//   [n4f, n4f+n4w)      : W float4 -> bf16x4
//   [n4f+n4w, +E)       : edge e -> two atomicAdds on cnt, store ranks
// ---------------------------------------------------------------------------
__global__ __launch_bounds__(256) void prep_kernel(
    const float* __restrict__ feat, unsigned short* __restrict__ featb, int n4f,
    const float* __restrict__ W, unsigned short* __restrict__ Wb, int n4w,
    const int* __restrict__ src, const int* __restrict__ dst,
    int* __restrict__ cnt, int* __restrict__ rankF, int* __restrict__ rankB,
    int E, int N)
{
    int i = blockIdx.x * blockDim.x + threadIdx.x;
    const int stride = gridDim.x * blockDim.x;
    const int total = n4f + n4w + E;
    for (; i < total; i += stride) {
        if (i < n4f + n4w) {
            const float* x; unsigned short* y; int j;
            if (i < n4f) { x = feat; y = featb; j = i; }
            else         { x = W;    y = Wb;    j = i - n4f; }
            float4 v = *reinterpret_cast<const float4*>(&x[(size_t)j * 4]);
            uint2 o;
            o.x = pack2bf(v.x, v.y);
            o.y = pack2bf(v.z, v.w);
            *reinterpret_cast<uint2*>(&y[(size_t)j * 4]) = o;
        } else {
            const int e = i - n4f - n4w;
            rankF[e] = atomicAdd(&cnt[dst[e]], 1);
            rankB[e] = atomicAdd(&cnt[N + src[e]], 1);
        }
    }
}

// ---------------------------------------------------------------------------
// scan1: per-block (CHUNK=1024) sums of cnt into blk[] (R5-proven).
// ---------------------------------------------------------------------------
__global__ __launch_bounds__(256) void scan1_kernel(
    const int* __restrict__ cnt, int* __restrict__ blk, int n2)
{
    __shared__ int red[256];
    const int b = blockIdx.x, t = threadIdx.x;
    const int base = b * CHUNK + t * 4;
    int s = 0;
    if (base + 3 < n2) {
        int4 v = *reinterpret_cast<const int4*>(&cnt[base]);
        s = v.x + v.y + v.z + v.w;
    } else {
        for (int j = 0; j < 4; ++j) { int idx = base + j; if (idx < n2) s += cnt[idx]; }
    }
    red[t] = s; __syncthreads();
    for (int o = 128; o > 0; o >>= 1) { if (t < o) red[t] += red[t + o]; __syncthreads(); }
    if (t == 0) blk[b] = red[0];
}

// ---------------------------------------------------------------------------
// scan3 (scan2 folded in): every block self-scans the NB block sums in LDS
// (NB=196 <= 256, 784B read — trivial), then computes its chunk's exclusive
// prefix and writes off[] (IMMUTABLE afterwards). No cur[] anymore.
// ---------------------------------------------------------------------------
__global__ __launch_bounds__(256) void scan3_kernel(
    const int* __restrict__ cnt, const int* __restrict__ blk,
    int* __restrict__ off, int n2, int total, int NB)
{
    __shared__ int sh[256];
    __shared__ int bs[256];
    const int b = blockIdx.x, t = threadIdx.x;

    // self-scan of block sums (inclusive)
    bs[t] = (t < NB) ? blk[t] : 0;
    __syncthreads();
    for (int o = 1; o < 256; o <<= 1) {
        int v = (t >= o) ? bs[t - o] : 0;
        __syncthreads();
        bs[t] += v;
        __syncthreads();
    }
    const int blkpref = (b > 0) ? bs[b - 1] : 0;

    const int base = b * CHUNK + t * 4;
    int v[4]; int s = 0;
    for (int j = 0; j < 4; ++j) { int idx = base + j; v[j] = (idx < n2) ? cnt[idx] : 0; s += v[j]; }
    sh[t] = s; __syncthreads();
    for (int o = 1; o < 256; o <<= 1) {
        int x = (t >= o) ? sh[t - o] : 0;
        __syncthreads();
        sh[t] += x;
        __syncthreads();
    }
    int excl = blkpref + ((t > 0) ? sh[t - 1] : 0);
    for (int j = 0; j < 4; ++j) {
        int idx = base + j;
        if (idx < n2) off[idx] = excl;
        excl += v[j];
    }
    if (b == 0 && t == 0) off[n2] = total;
}

// ---------------------------------------------------------------------------
// Scatter edge ids: ATOMIC-FREE (slot = off[seg] + rank from prep-hist),
// node-range partitioned for XCD write locality (R6-proven). rank loads are
// predicated on ownership (exec-masked), so most lanes skip them.
// ---------------------------------------------------------------------------
__global__ __launch_bounds__(256) void scatter_ids_kernel(
    const int* __restrict__ src, const int* __restrict__ dst,
    const int* __restrict__ off,
    const int* __restrict__ rankF, const int* __restrict__ rankB,
    int* __restrict__ csr, int E, int N, int npr)
{
    const int grp = blockIdx.x & (NXCD - 1);
    const int bIn = blockIdx.x >> 3;
    const int nbk = gridDim.x >> 3;
    const int lo = grp * npr;
    const int hi = lo + npr;

    int i = bIn * 256 + threadIdx.x;
    const int stride = nbk * 256;
    for (int e = i; e < E; e += stride) {
        const int s = src[e];
        const int d = dst[e];
        if (d >= lo && d < hi) {
            csr[off[d] + rankF[e]] = s;
        }
        if (s >= lo && s < hi) {
            csr[off[N + s] + rankB[e]] = d;
        }
    }
}

// ---------------------------------------------------------------------------
// Phase B: gather means (R10 code, byte-identical). 16 lanes per segment;
// lane l owns bf16 columns [8l, 8l+8). Bounds from IMMUTABLE off.
// ---------------------------------------------------------------------------
__global__ __launch_bounds__(256) void gather_mean_kernel(
    const unsigned short* __restrict__ featb, const int* __restrict__ off,
    const int* __restrict__ csr, unsigned short* __restrict__ meanb, int n2)
{
    const int tid = blockIdx.x * 256 + threadIdx.x;
    const int seg = tid >> 4;
    const int l = tid & 15;
    if (seg >= n2) return;

    const int beg = off[seg], end = off[seg + 1];
    float a0=0,a1=0,a2=0,a3=0,a4=0,a5=0,a6=0,a7=0;

    int e = beg;
    for (; e + 3 < end; e += 4) {
        const int n0 = csr[e], n1 = csr[e + 1], n2i = csr[e + 2], n3 = csr[e + 3];
        const uint4 v0 = *reinterpret_cast<const uint4*>(featb + (size_t)n0 * D + l * 8);
        const uint4 v1 = *reinterpret_cast<const uint4*>(featb + (size_t)n1 * D + l * 8);
        const uint4 v2 = *reinterpret_cast<const uint4*>(featb + (size_t)n2i * D + l * 8);
        const uint4 v3 = *reinterpret_cast<const uint4*>(featb + (size_t)n3 * D + l * 8);
        a0 += (bflo(v0.x) + bflo(v1.x)) + (bflo(v2.x) + bflo(v3.x));
        a1 += (bfhi(v0.x) + bfhi(v1.x)) + (bfhi(v2.x) + bfhi(v3.x));
        a2 += (bflo(v0.y) + bflo(v1.y)) + (bflo(v2.y) + bflo(v3.y));
        a3 += (bfhi(v0.y) + bfhi(v1.y)) + (bfhi(v2.y) + bfhi(v3.y));
        a4 += (bflo(v0.z) + bflo(v1.z)) + (bflo(v2.z) + bflo(v3.z));
        a5 += (bfhi(v0.z) + bfhi(v1.z)) + (bfhi(v2.z) + bfhi(v3.z));
        a6 += (bflo(v0.w) + bflo(v1.w)) + (bflo(v2.w) + bflo(v3.w));
        a7 += (bfhi(v0.w) + bfhi(v1.w)) + (bfhi(v2.w) + bfhi(v3.w));
    }
    for (; e < end; ++e) {
        const int n0 = csr[e];
        const uint4 v0 = *reinterpret_cast<const uint4*>(featb + (size_t)n0 * D + l * 8);
        a0 += bflo(v0.x); a1 += bfhi(v0.x);
        a2 += bflo(v0.y); a3 += bfhi(v0.y);
        a4 += bflo(v0.z); a5 += bfhi(v0.z);
        a6 += bflo(v0.w); a7 += bfhi(v0.w);
    }

    const int deg = end - beg;
    const float inv = 1.0f / (float)((deg > 1) ? deg : 1);
    uint4 o;
    o.x = pack2bf(a0 * inv, a1 * inv);
    o.y = pack2bf(a2 * inv, a3 * inv);
    o.z = pack2bf(a4 * inv, a5 * inv);
    o.w = pack2bf(a6 * inv, a7 * inv);
    *reinterpret_cast<uint4*>(meanb + (size_t)seg * D + l * 8) = o;
}

// ---------------------------------------------------------------------------
// Phase C: bf16 MFMA GEMM v3 (R9-proven, byte-identical). 512 thr, 128
// rows/block, K=128 LDS slabs double-buffered (3 barriers), XOR-swizzled,
// all 12 A-frags register-prefetched, operand-swapped mfma(w,h), float4
// epilogue.
// ---------------------------------------------------------------------------
__global__ __launch_bounds__(512) void mfma_gemm_kernel(
    const unsigned short* __restrict__ featb,
    const unsigned short* __restrict__ meanb,
    const unsigned short* __restrict__ Wb,      // [128][384] bf16
    float* __restrict__ out, int N)
{
    __shared__ unsigned short wlds[2][128 * 128];   // 2 x 32KB, swizzled [col][k]

    const int t = threadIdx.x;
    const int wv = t >> 6;          // 0..7
    const int lane = t & 63;
    const int r = lane & 15;
    const int q = lane >> 4;        // 0..3

    const int row0 = blockIdx.x * 128 + wv * 16;
    const int row = row0 + r;
    const int rowc = (row < N) ? row : (N - 1);

    // ---- prefetch all 12 A-fragments ----
    const unsigned short* h0 = featb + (size_t)rowc * D;
    const unsigned short* h1 = meanb + (size_t)rowc * D;
    const unsigned short* h2 = meanb + ((size_t)N + rowc) * D;
    bf16x8 af[12];
#pragma unroll
    for (int kk = 0; kk < 4; ++kk) {
        af[kk]     = *reinterpret_cast<const bf16x8*>(h0 + kk * 32 + q * 8);
        af[4 + kk] = *reinterpret_cast<const bf16x8*>(h1 + kk * 32 + q * 8);
        af[8 + kk] = *reinterpret_cast<const bf16x8*>(h2 + kk * 32 + q * 8);
    }

    // ---- W staging: thread t owns col sc, 4 x 16B sub-chunks ----
    const int sc = t >> 2;          // 0..127
    const int sq = t & 3;           // 0..3
    const char* wsrc = reinterpret_cast<const char*>(Wb) + (size_t)sc * 768;
    const int swz = (sc & 7) << 4;

    f32x4 acc[8];
#pragma unroll
    for (int n = 0; n < 8; ++n) acc[n] = (f32x4){0.f, 0.f, 0.f, 0.f};

    // prologue: stage slab 0 into buf 0
    {
        uint4 st[4];
#pragma unroll
        for (int j = 0; j < 4; ++j)
            st[j] = *reinterpret_cast<const uint4*>(wsrc + j * 64 + sq * 16);
        char* wb0 = reinterpret_cast<char*>(&wlds[0][0]) + sc * 256;
#pragma unroll
        for (int j = 0; j < 4; ++j)
            *reinterpret_cast<uint4*>(wb0 + ((j * 64 + sq * 16) ^ swz)) = st[j];
    }
    __syncthreads();

#pragma unroll
    for (int ci = 0; ci < 3; ++ci) {
        // issue next-slab loads early (latency hides under compute below)
        uint4 nx[4];
        if (ci < 2) {
#pragma unroll
            for (int j = 0; j < 4; ++j)
                nx[j] = *reinterpret_cast<const uint4*>(
                    wsrc + (ci + 1) * 256 + j * 64 + sq * 16);
        }

        const char* wl = reinterpret_cast<const char*>(&wlds[ci & 1][0]);
#pragma unroll
        for (int kk = 0; kk < 4; ++kk) {
            const bf16x8 bh = af[ci * 4 + kk];
#pragma unroll
            for (int n = 0; n < 8; ++n) {
                const int c = n * 16 + r;
                const bf16x8 aw = *reinterpret_cast<const bf16x8*>(
                    wl + c * 256 + ((kk * 64 + q * 16) ^ ((c & 7) << 4)));
                acc[n] = __builtin_amdgcn_mfma_f32_16x16x32_bf16(aw, bh, acc[n], 0, 0, 0);
            }
        }

        if (ci < 2) {
            char* wbn = reinterpret_cast<char*>(&wlds[(ci + 1) & 1][0]) + sc * 256;
#pragma unroll
            for (int j = 0; j < 4; ++j)
                *reinterpret_cast<uint4*>(wbn + ((j * 64 + sq * 16) ^ swz)) = nx[j];
            __syncthreads();
        }
    }

    // epilogue: lane (q,r) holds out[row0+r][n*16 + q*4 + i], i=0..3
    if (row < N) {
        float* orow = out + (size_t)row * D;
#pragma unroll
        for (int n = 0; n < 8; ++n) {
            float4 v;
            v.x = fmaxf(acc[n][0], 0.0f);
            v.y = fmaxf(acc[n][1], 0.0f);
            v.z = fmaxf(acc[n][2], 0.0f);
            v.w = fmaxf(acc[n][3], 0.0f);
            *reinterpret_cast<float4*>(orow + n * 16 + q * 4) = v;
        }
    }
}

// ---------------------------------------------------------------------------
extern "C" void kernel_launch(void* const* d_in, const int* in_sizes, int n_in,
                              void* d_out, int out_size, void* d_ws, size_t ws_size,
                              hipStream_t stream) {
    const float* feat = (const float*)d_in[0];
    const float* W    = (const float*)d_in[1];
    const int*   ei   = (const int*)d_in[2];
    float*       out  = (float*)d_out;

    const int E = in_sizes[2] / 2;           // 800000
    const int N = in_sizes[0] / D;           // 100000
    const int n2 = 2 * N;
    const int* src = ei;
    const int* dst = ei + E;

    // ws layout (4B units then 2B units, all 16B-aligned):
    // cnt[n2] | off[n2+4] | blk[256] | rankF[E] | rankB[E] | csr[2E] |
    // featb[N*D] u16 | Wb[128*384] u16 | meanb[n2*D] u16
    int* cnt   = (int*)d_ws;
    int* off   = cnt + n2;
    int* blk   = off + (n2 + 4);
    int* rankF = blk + 256;
    int* rankB = rankF + E;
    int* csr   = rankB + E;
    unsigned short* featb = (unsigned short*)(csr + 2 * E);
    unsigned short* Wb    = featb + (size_t)N * D;
    unsigned short* meanb = Wb + 128 * 384;

    // zero cnt only (off written by scan3; ranks by prep; csr by scatter)
    hipMemsetAsync(cnt, 0, (size_t)n2 * sizeof(int), stream);

    const int NB = (n2 + CHUNK - 1) / CHUNK; // 196
    const int npr = (N + NXCD - 1) / NXCD;   // 12500 nodes per range
    const int n4f = N * D / 4;
    const int n4w = 128 * 384 / 4;

    prep_kernel<<<2048, 256, 0, stream>>>(feat, featb, n4f, W, Wb, n4w,
                                          src, dst, cnt, rankF, rankB, E, N);

    scan1_kernel<<<NB, 256, 0, stream>>>(cnt, blk, n2);
    scan3_kernel<<<NB, 256, 0, stream>>>(cnt, blk, off, n2, 2 * E, NB);
    scatter_ids_kernel<<<2048, 256, 0, stream>>>(src, dst, off, rankF, rankB,
                                                 csr, E, N, npr);

    const int gather_blocks = (n2 * 16 + 255) / 256;   // 16 lanes per segment
    gather_mean_kernel<<<gather_blocks, 256, 0, stream>>>(featb, off, csr, meanb, n2);

    mfma_gemm_kernel<<<(N + 127) / 128, 512, 0, stream>>>(featb, meanb, Wb, out, N);
}

// Round 12
// 227.224 us; speedup vs baseline: 1.4614x; 1.0495x over previous
//
#include <hip/hip_runtime.h>
#include <hip/hip_bf16.h>

#define D 128
#define CHUNK 1024   // elements per scan block (256 thr x 4)
#define NXCD 8

typedef __attribute__((ext_vector_type(8))) short bf16x8;
typedef __attribute__((ext_vector_type(4))) float f32x4;

// ---- bf16 helpers (bit-level, RNE via __float2bfloat16) --------------------
__device__ inline float bflo(unsigned u) { return __uint_as_float(u << 16); }
__device__ inline float bfhi(unsigned u) { return __uint_as_float(u & 0xffff0000u); }
__device__ inline unsigned short f2bf(float f) {
    __hip_bfloat16 h = __float2bfloat16(f);
    return *reinterpret_cast<unsigned short*>(&h);
}
__device__ inline unsigned pack2bf(float lo, float hi) {
    return (unsigned)f2bf(lo) | ((unsigned)f2bf(hi) << 16);
}

// ---------------------------------------------------------------------------
// convert: fp32->bf16 for feat and W. Pure streaming (BW-bound), no atomics.
// ---------------------------------------------------------------------------
__global__ __launch_bounds__(256) void convert_kernel(
    const float* __restrict__ feat, unsigned short* __restrict__ featb, int n4f,
    const float* __restrict__ W, unsigned short* __restrict__ Wb, int n4w)
{
    int i = blockIdx.x * blockDim.x + threadIdx.x;
    const int stride = gridDim.x * blockDim.x;
    const int n4 = n4f + n4w;
    for (; i < n4; i += stride) {
        const float* x; unsigned short* y; int j;
        if (i < n4f) { x = feat; y = featb; j = i; }
        else         { x = W;    y = Wb;    j = i - n4f; }
        float4 v = *reinterpret_cast<const float4*>(&x[(size_t)j * 4]);
        uint2 o;
        o.x = pack2bf(v.x, v.y);
        o.y = pack2bf(v.z, v.w);
        *reinterpret_cast<uint2*>(&y[(size_t)j * 4]) = o;
    }
}

// ---------------------------------------------------------------------------
// hist+rank: one thread per edge. The atomic RETURN value is the edge's rank
// within its segment (makes scatter atomic-free). Latency-bound; 800K
// threads of pure TLP hide the ~700cy atomic round-trip.
// ---------------------------------------------------------------------------
__global__ __launch_bounds__(256) void hist_rank_kernel(
    const int* __restrict__ src, const int* __restrict__ dst,
    int* __restrict__ cnt, int* __restrict__ rankF, int* __restrict__ rankB,
    int E, int N)
{
    const int e = blockIdx.x * blockDim.x + threadIdx.x;
    if (e < E) {
        rankF[e] = atomicAdd(&cnt[dst[e]], 1);
        rankB[e] = atomicAdd(&cnt[N + src[e]], 1);
    }
}

// ---------------------------------------------------------------------------
// scan1: per-block (CHUNK=1024) sums of cnt into blk[] (R5-proven).
// ---------------------------------------------------------------------------
__global__ __launch_bounds__(256) void scan1_kernel(
    const int* __restrict__ cnt, int* __restrict__ blk, int n2)
{
    __shared__ int red[256];
    const int b = blockIdx.x, t = threadIdx.x;
    const int base = b * CHUNK + t * 4;
    int s = 0;
    if (base + 3 < n2) {
        int4 v = *reinterpret_cast<const int4*>(&cnt[base]);
        s = v.x + v.y + v.z + v.w;
    } else {
        for (int j = 0; j < 4; ++j) { int idx = base + j; if (idx < n2) s += cnt[idx]; }
    }
    red[t] = s; __syncthreads();
    for (int o = 128; o > 0; o >>= 1) { if (t < o) red[t] += red[t + o]; __syncthreads(); }
    if (t == 0) blk[b] = red[0];
}

// ---------------------------------------------------------------------------
// scan3 (scan2 folded in): every block self-scans the NB block sums in LDS,
// then computes its chunk's exclusive prefix and writes off[] (IMMUTABLE
// afterwards).
// ---------------------------------------------------------------------------
__global__ __launch_bounds__(256) void scan3_kernel(
    const int* __restrict__ cnt, const int* __restrict__ blk,
    int* __restrict__ off, int n2, int total, int NB)
{
    __shared__ int sh[256];
    __shared__ int bs[256];
    const int b = blockIdx.x, t = threadIdx.x;

    bs[t] = (t < NB) ? blk[t] : 0;
    __syncthreads();
    for (int o = 1; o < 256; o <<= 1) {
        int v = (t >= o) ? bs[t - o] : 0;
        __syncthreads();
        bs[t] += v;
        __syncthreads();
    }
    const int blkpref = (b > 0) ? bs[b - 1] : 0;

    const int base = b * CHUNK + t * 4;
    int v[4]; int s = 0;
    for (int j = 0; j < 4; ++j) { int idx = base + j; v[j] = (idx < n2) ? cnt[idx] : 0; s += v[j]; }
    sh[t] = s; __syncthreads();
    for (int o = 1; o < 256; o <<= 1) {
        int x = (t >= o) ? sh[t - o] : 0;
        __syncthreads();
        sh[t] += x;
        __syncthreads();
    }
    int excl = blkpref + ((t > 0) ? sh[t - 1] : 0);
    for (int j = 0; j < 4; ++j) {
        int idx = base + j;
        if (idx < n2) off[idx] = excl;
        excl += v[j];
    }
    if (b == 0 && t == 0) off[n2] = total;
}

// ---------------------------------------------------------------------------
// Scatter edge ids: ATOMIC-FREE (slot = off[seg] + rank from hist),
// node-range partitioned for XCD write locality (R6-proven).
// ---------------------------------------------------------------------------
__global__ __launch_bounds__(256) void scatter_ids_kernel(
    const int* __restrict__ src, const int* __restrict__ dst,
    const int* __restrict__ off,
    const int* __restrict__ rankF, const int* __restrict__ rankB,
    int* __restrict__ csr, int E, int N, int npr)
{
    const int grp = blockIdx.x & (NXCD - 1);
    const int bIn = blockIdx.x >> 3;
    const int nbk = gridDim.x >> 3;
    const int lo = grp * npr;
    const int hi = lo + npr;

    int i = bIn * 256 + threadIdx.x;
    const int stride = nbk * 256;
    for (int e = i; e < E; e += stride) {
        const int s = src[e];
        const int d = dst[e];
        if (d >= lo && d < hi) {
            csr[off[d] + rankF[e]] = s;
        }
        if (s >= lo && s < hi) {
            csr[off[N + s] + rankB[e]] = d;
        }
    }
}

// ---------------------------------------------------------------------------
// Phase B: gather means (R10-proven, byte-identical). 16 lanes per segment;
// lane l owns bf16 columns [8l, 8l+8). Bounds from IMMUTABLE off.
// ---------------------------------------------------------------------------
__global__ __launch_bounds__(256) void gather_mean_kernel(
    const unsigned short* __restrict__ featb, const int* __restrict__ off,
    const int* __restrict__ csr, unsigned short* __restrict__ meanb, int n2)
{
    const int tid = blockIdx.x * 256 + threadIdx.x;
    const int seg = tid >> 4;
    const int l = tid & 15;
    if (seg >= n2) return;

    const int beg = off[seg], end = off[seg + 1];
    float a0=0,a1=0,a2=0,a3=0,a4=0,a5=0,a6=0,a7=0;

    int e = beg;
    for (; e + 3 < end; e += 4) {
        const int n0 = csr[e], n1 = csr[e + 1], n2i = csr[e + 2], n3 = csr[e + 3];
        const uint4 v0 = *reinterpret_cast<const uint4*>(featb + (size_t)n0 * D + l * 8);
        const uint4 v1 = *reinterpret_cast<const uint4*>(featb + (size_t)n1 * D + l * 8);
        const uint4 v2 = *reinterpret_cast<const uint4*>(featb + (size_t)n2i * D + l * 8);
        const uint4 v3 = *reinterpret_cast<const uint4*>(featb + (size_t)n3 * D + l * 8);
        a0 += (bflo(v0.x) + bflo(v1.x)) + (bflo(v2.x) + bflo(v3.x));
        a1 += (bfhi(v0.x) + bfhi(v1.x)) + (bfhi(v2.x) + bfhi(v3.x));
        a2 += (bflo(v0.y) + bflo(v1.y)) + (bflo(v2.y) + bflo(v3.y));
        a3 += (bfhi(v0.y) + bfhi(v1.y)) + (bfhi(v2.y) + bfhi(v3.y));
        a4 += (bflo(v0.z) + bflo(v1.z)) + (bflo(v2.z) + bflo(v3.z));
        a5 += (bfhi(v0.z) + bfhi(v1.z)) + (bfhi(v2.z) + bfhi(v3.z));
        a6 += (bflo(v0.w) + bflo(v1.w)) + (bflo(v2.w) + bflo(v3.w));
        a7 += (bfhi(v0.w) + bfhi(v1.w)) + (bfhi(v2.w) + bfhi(v3.w));
    }
    for (; e < end; ++e) {
        const int n0 = csr[e];
        const uint4 v0 = *reinterpret_cast<const uint4*>(featb + (size_t)n0 * D + l * 8);
        a0 += bflo(v0.x); a1 += bfhi(v0.x);
        a2 += bflo(v0.y); a3 += bfhi(v0.y);
        a4 += bflo(v0.z); a5 += bfhi(v0.z);
        a6 += bflo(v0.w); a7 += bfhi(v0.w);
    }

    const int deg = end - beg;
    const float inv = 1.0f / (float)((deg > 1) ? deg : 1);
    uint4 o;
    o.x = pack2bf(a0 * inv, a1 * inv);
    o.y = pack2bf(a2 * inv, a3 * inv);
    o.z = pack2bf(a4 * inv, a5 * inv);
    o.w = pack2bf(a6 * inv, a7 * inv);
    *reinterpret_cast<uint4*>(meanb + (size_t)seg * D + l * 8) = o;
}

// ---------------------------------------------------------------------------
// Phase C: bf16 MFMA GEMM v3 (R9-proven, byte-identical). 512 thr, 128
// rows/block, K=128 LDS slabs double-buffered (3 barriers), XOR-swizzled,
// all 12 A-frags register-prefetched, operand-swapped mfma(w,h), float4
// epilogue.
// ---------------------------------------------------------------------------
__global__ __launch_bounds__(512) void mfma_gemm_kernel(
    const unsigned short* __restrict__ featb,
    const unsigned short* __restrict__ meanb,
    const unsigned short* __restrict__ Wb,      // [128][384] bf16
    float* __restrict__ out, int N)
{
    __shared__ unsigned short wlds[2][128 * 128];   // 2 x 32KB, swizzled [col][k]

    const int t = threadIdx.x;
    const int wv = t >> 6;          // 0..7
    const int lane = t & 63;
    const int r = lane & 15;
    const int q = lane >> 4;        // 0..3

    const int row0 = blockIdx.x * 128 + wv * 16;
    const int row = row0 + r;
    const int rowc = (row < N) ? row : (N - 1);

    // ---- prefetch all 12 A-fragments ----
    const unsigned short* h0 = featb + (size_t)rowc * D;
    const unsigned short* h1 = meanb + (size_t)rowc * D;
    const unsigned short* h2 = meanb + ((size_t)N + rowc) * D;
    bf16x8 af[12];
#pragma unroll
    for (int kk = 0; kk < 4; ++kk) {
        af[kk]     = *reinterpret_cast<const bf16x8*>(h0 + kk * 32 + q * 8);
        af[4 + kk] = *reinterpret_cast<const bf16x8*>(h1 + kk * 32 + q * 8);
        af[8 + kk] = *reinterpret_cast<const bf16x8*>(h2 + kk * 32 + q * 8);
    }

    // ---- W staging: thread t owns col sc, 4 x 16B sub-chunks ----
    const int sc = t >> 2;          // 0..127
    const int sq = t & 3;           // 0..3
    const char* wsrc = reinterpret_cast<const char*>(Wb) + (size_t)sc * 768;
    const int swz = (sc & 7) << 4;

    f32x4 acc[8];
#pragma unroll
    for (int n = 0; n < 8; ++n) acc[n] = (f32x4){0.f, 0.f, 0.f, 0.f};

    // prologue: stage slab 0 into buf 0
    {
        uint4 st[4];
#pragma unroll
        for (int j = 0; j < 4; ++j)
            st[j] = *reinterpret_cast<const uint4*>(wsrc + j * 64 + sq * 16);
        char* wb0 = reinterpret_cast<char*>(&wlds[0][0]) + sc * 256;
#pragma unroll
        for (int j = 0; j < 4; ++j)
            *reinterpret_cast<uint4*>(wb0 + ((j * 64 + sq * 16) ^ swz)) = st[j];
    }
    __syncthreads();

#pragma unroll
    for (int ci = 0; ci < 3; ++ci) {
        uint4 nx[4];
        if (ci < 2) {
#pragma unroll
            for (int j = 0; j < 4; ++j)
                nx[j] = *reinterpret_cast<const uint4*>(
                    wsrc + (ci + 1) * 256 + j * 64 + sq * 16);
        }

        const char* wl = reinterpret_cast<const char*>(&wlds[ci & 1][0]);
#pragma unroll
        for (int kk = 0; kk < 4; ++kk) {
            const bf16x8 bh = af[ci * 4 + kk];
#pragma unroll
            for (int n = 0; n < 8; ++n) {
                const int c = n * 16 + r;
                const bf16x8 aw = *reinterpret_cast<const bf16x8*>(
                    wl + c * 256 + ((kk * 64 + q * 16) ^ ((c & 7) << 4)));
                acc[n] = __builtin_amdgcn_mfma_f32_16x16x32_bf16(aw, bh, acc[n], 0, 0, 0);
            }
        }

        if (ci < 2) {
            char* wbn = reinterpret_cast<char*>(&wlds[(ci + 1) & 1][0]) + sc * 256;
#pragma unroll
            for (int j = 0; j < 4; ++j)
                *reinterpret_cast<uint4*>(wbn + ((j * 64 + sq * 16) ^ swz)) = nx[j];
            __syncthreads();
        }
    }

    // epilogue: lane (q,r) holds out[row0+r][n*16 + q*4 + i], i=0..3
    if (row < N) {
        float* orow = out + (size_t)row * D;
#pragma unroll
        for (int n = 0; n < 8; ++n) {
            float4 v;
            v.x = fmaxf(acc[n][0], 0.0f);
            v.y = fmaxf(acc[n][1], 0.0f);
            v.z = fmaxf(acc[n][2], 0.0f);
            v.w = fmaxf(acc[n][3], 0.0f);
            *reinterpret_cast<float4*>(orow + n * 16 + q * 4) = v;
        }
    }
}

// ---------------------------------------------------------------------------
extern "C" void kernel_launch(void* const* d_in, const int* in_sizes, int n_in,
                              void* d_out, int out_size, void* d_ws, size_t ws_size,
                              hipStream_t stream) {
    const float* feat = (const float*)d_in[0];
    const float* W    = (const float*)d_in[1];
    const int*   ei   = (const int*)d_in[2];
    float*       out  = (float*)d_out;

    const int E = in_sizes[2] / 2;           // 800000
    const int N = in_sizes[0] / D;           // 100000
    const int n2 = 2 * N;
    const int* src = ei;
    const int* dst = ei + E;

    // ws layout (4B units then 2B units, all 16B-aligned):
    // cnt[n2] | off[n2+4] | blk[256] | rankF[E] | rankB[E] | csr[2E] |
    // featb[N*D] u16 | Wb[128*384] u16 | meanb[n2*D] u16
    int* cnt   = (int*)d_ws;
    int* off   = cnt + n2;
    int* blk   = off + (n2 + 4);
    int* rankF = blk + 256;
    int* rankB = rankF + E;
    int* csr   = rankB + E;
    unsigned short* featb = (unsigned short*)(csr + 2 * E);
    unsigned short* Wb    = featb + (size_t)N * D;
    unsigned short* meanb = Wb + 128 * 384;

    // zero cnt only (off written by scan3; ranks by hist; csr by scatter)
    hipMemsetAsync(cnt, 0, (size_t)n2 * sizeof(int), stream);

    const int NB = (n2 + CHUNK - 1) / CHUNK; // 196
    const int npr = (N + NXCD - 1) / NXCD;   // 12500 nodes per range
    const int n4f = N * D / 4;
    const int n4w = 128 * 384 / 4;

    convert_kernel<<<2048, 256, 0, stream>>>(feat, featb, n4f, W, Wb, n4w);
    hist_rank_kernel<<<(E + 255) / 256, 256, 0, stream>>>(src, dst, cnt,
                                                          rankF, rankB, E, N);

    scan1_kernel<<<NB, 256, 0, stream>>>(cnt, blk, n2);
    scan3_kernel<<<NB, 256, 0, stream>>>(cnt, blk, off, n2, 2 * E, NB);
    scatter_ids_kernel<<<2048, 256, 0, stream>>>(src, dst, off, rankF, rankB,
                                                 csr, E, N, npr);

    const int gather_blocks = (n2 * 16 + 255) / 256;   // 16 lanes per segment
    gather_mean_kernel<<<gather_blocks, 256, 0, stream>>>(featb, off, csr, meanb, n2);

    mfma_gemm_kernel<<<(N + 127) / 128, 512, 0, stream>>>(featb, meanb, Wb, out, N);
}